// Round 6
// baseline (2408.123 us; speedup 1.0000x reference)
//
#include <hip/hip_runtime.h>
#include <stdint.h>

// Problem constants (bench-fixed): N=50000 (< 65536 -> src fits u16), E=800000
#define NF 29
#define HD 64
#define NL 7
#define LDW 72      // padded bf16 row stride for weight/t1 tiles (144 B)
#define NCHUNK 64   // edge chunks for tile-binned scatter
#define NBP 1024    // padded bucket stride (ceil(N/64)=782 <= 1024)

typedef __attribute__((ext_vector_type(8))) __bf16 bf16x8;
typedef __attribute__((ext_vector_type(4))) float floatx4;

__device__ __forceinline__ unsigned short f2bf(float x) {
    unsigned u = __float_as_uint(x);
    unsigned r = (u + 0x7fffu + ((u >> 16) & 1u)) >> 16;
    return (unsigned short)r;
}
__device__ __forceinline__ unsigned pack_bf2(float x, float y) {
    return (unsigned)f2bf(x) | ((unsigned)f2bf(y) << 16);
}
__device__ __forceinline__ float bf2f(unsigned short s) {
    return __uint_as_float((uint32_t)s << 16);
}

// ---------------- h0 = concat(x, pos) -> bf16 ----------------
__global__ void build_h0_kernel(const float* __restrict__ x, const float* __restrict__ pos,
                                unsigned short* __restrict__ h0, int N) {
    int t = blockIdx.x * blockDim.x + threadIdx.x;
    if (t >= N * 32) return;
    int n = t >> 5, f = t & 31;
    float v = (f < NF) ? x[n * NF + f] : pos[n * 3 + (f - NF)];
    h0[t] = f2bf(v);
}

// ---------------- weights: fp32 -> transposed, padded bf16 ----------------
__global__ void prep_weights_kernel(const float* __restrict__ W1f, const float* __restrict__ W1r,
                                    const float* __restrict__ W2, unsigned short* __restrict__ wpk) {
    const int PER_M = 64 * LDW;
    int t = blockIdx.x * blockDim.x + threadIdx.x;
    if (t >= NL * 2 * PER_M) return;
    int l = t / (2 * PER_M);
    int r = t - l * 2 * PER_M;
    int m = r / PER_M;
    int q = r - m * PER_M;
    int j = q / LDW, k = q - j * LDW;
    float v = 0.f;
    if (m == 0) {
        int ind = (l == 0) ? 32 : 64;
        if (k < ind) v = (l == 0) ? W1f[k * 64 + j]
                                  : W1r[(size_t)(l - 1) * 4096 + (size_t)k * 64 + j];
    } else {
        if (k < 64) v = W2[(size_t)l * 4096 + (size_t)k * 64 + j];
    }
    wpk[t] = f2bf(v);
}

// ---------------- tile-binned edge build (bucket = dst >> 6) ----------------
__global__ void tile_hist_kernel(const int* __restrict__ dst, int E, int chunk,
                                 int* __restrict__ bcnt, int nb) {
    __shared__ int hist[NBP];
    int tid = threadIdx.x;
    for (int i = tid; i < NBP; i += 256) hist[i] = 0;
    __syncthreads();
    int lo = blockIdx.x * chunk, hi = min(E, lo + chunk);
    for (int e = lo + tid; e < hi; e += 256) atomicAdd(&hist[dst[e] >> 6], 1);
    __syncthreads();
    for (int i = tid; i < nb; i += 256) bcnt[blockIdx.x * NBP + i] = hist[i];
}

__global__ void tile_scan_kernel(const int* __restrict__ bcnt, int* __restrict__ boff,
                                 int* __restrict__ tstart, int nb, int E) {
    __shared__ int s[1024];
    int t = threadIdx.x;
    int tot = 0;
    if (t < nb)
        for (int blk = 0; blk < NCHUNK; ++blk) tot += bcnt[blk * NBP + t];
    s[t] = tot;
    __syncthreads();
    for (int off = 1; off < 1024; off <<= 1) {
        int v = (t >= off) ? s[t - off] : 0;
        __syncthreads();
        s[t] += v;
        __syncthreads();
    }
    int start = (t == 0) ? 0 : s[t - 1];
    if (t < nb) {
        tstart[t] = start;
        int run = start;
        for (int blk = 0; blk < NCHUNK; ++blk) {
            boff[blk * NBP + t] = run;
            run += bcnt[blk * NBP + t];
        }
    }
    if (t == 0) tstart[nb] = E;
}

// epk[p] = src | (dstLocal << 16)   (requires N <= 65536)
__global__ void tile_scatter_kernel(const int* __restrict__ src, const int* __restrict__ dst,
                                    int E, int chunk, const int* __restrict__ boff,
                                    unsigned int* __restrict__ epk, int nb) {
    __shared__ int cur[NBP];
    int tid = threadIdx.x;
    for (int i = tid; i < nb; i += 256) cur[i] = boff[blockIdx.x * NBP + i];
    __syncthreads();
    int lo = blockIdx.x * chunk, hi = min(E, lo + chunk);
    for (int e = lo + tid; e < hi; e += 256) {
        int d = dst[e];
        int p = atomicAdd(&cur[d >> 6], 1);
        epk[p] = (unsigned int)src[e] | ((unsigned int)(d & 63) << 16);
    }
}

// ---------------- fused GIN layer: edge-parallel gather + MFMA MLP ----------------
// Block = 512 threads (8 waves) = 64-node tile. Tile's edges are contiguous
// [tstart[b], tstart[b+1]). Gather: lane = feature; one edge = one coalesced
// row load + one ds_add_f32 into zacc (f32, stride 65 -> 2 lanes/bank = free).
// 8-deep unroll keeps 8 row-lines in flight per wave, no divergence, no tails.
template<int IND, bool RELU_OUT>
__global__ __launch_bounds__(512, 8)
void gin_layer_kernel(const unsigned short* __restrict__ hin,
                      const int* __restrict__ tstart, const unsigned int* __restrict__ epk,
                      const unsigned short* __restrict__ wAT, const unsigned short* __restrict__ wBT,
                      const float* __restrict__ ba, const float* __restrict__ bb,
                      unsigned short* __restrict__ hout, int N)
{
    constexpr int PAD = IND + 1;     // zacc row stride in f32
    __shared__ __align__(16) float zacc[64 * 65];               // 16.6 KB (hosts staging too)
    __shared__ __align__(16) unsigned short t1buf[64 * LDW];    // 9.2 KB
    __shared__ __align__(16) unsigned short waT[64 * LDW];
    __shared__ __align__(16) unsigned short wbT[64 * LDW];

    const int tid = threadIdx.x;
    const int lane = tid & 63;
    const int w = tid >> 6;
    const int tile0 = blockIdx.x * 64;

    // ---- stage pre-packed bf16 weights (uint4 memcpy) ----
    {
        const uint4* a4 = (const uint4*)wAT;
        const uint4* b4 = (const uint4*)wBT;
        uint4* da = (uint4*)waT;
        uint4* db = (uint4*)wbT;
        for (int i = tid; i < 64 * LDW / 8; i += 512) { da[i] = a4[i]; db[i] = b4[i]; }
    }

    // ---- init zacc with self term ----
    for (int i = tid; i < 64 * IND; i += 512) {
        int n = i / IND, f = i - n * IND;
        int node = tile0 + n;
        zacc[n * PAD + f] = (node < N) ? bf2f(hin[(size_t)node * IND + f]) : 0.f;
    }
    __syncthreads();

    // ---- edge-parallel gather ----
    const int e0 = tstart[blockIdx.x];
    const int e1 = tstart[blockIdx.x + 1];

    if constexpr (IND == 64) {
        for (int base = e0 + w * 8; base < e1; base += 64) {
            unsigned int pk[8];
            float v[8];
            #pragma unroll
            for (int q = 0; q < 8; ++q) pk[q] = (base + q < e1) ? epk[base + q] : 0u;
            #pragma unroll
            for (int q = 0; q < 8; ++q) {
                int s = pk[q] & 0xffff;
                v[q] = bf2f(hin[(size_t)s * 64 + lane]);
            }
            #pragma unroll
            for (int q = 0; q < 8; ++q) {
                if (base + q < e1) {
                    int dl = pk[q] >> 16;
                    atomicAdd(&zacc[dl * PAD + lane], v[q]);
                }
            }
        }
    } else {  // IND == 32: half-wave per edge -> 16 edges per unrolled block
        const int p = lane >> 5, f = lane & 31;
        for (int base = e0 + w * 16; base < e1; base += 128) {
            unsigned int pk[8];
            float v[8];
            #pragma unroll
            for (int q = 0; q < 8; ++q) {
                int eq = base + 2 * q + p;
                pk[q] = (eq < e1) ? epk[eq] : 0u;
            }
            #pragma unroll
            for (int q = 0; q < 8; ++q) {
                int s = pk[q] & 0xffff;
                v[q] = bf2f(hin[(size_t)s * 32 + f]);
            }
            #pragma unroll
            for (int q = 0; q < 8; ++q) {
                int eq = base + 2 * q + p;
                if (eq < e1) {
                    int dl = pk[q] >> 16;
                    atomicAdd(&zacc[dl * PAD + f], v[q]);
                }
            }
        }
    }
    __syncthreads();

    // ---- MFMA MLP ----
    const int n0 = lane & 15, quad = lane >> 4;
    const int stripe = w & 3, jhalf = w >> 2;
    const int row0 = stripe * 16;
    const int jt0 = jhalf * 2, jt1 = jhalf * 2 + 1;

    floatx4 c0, c1;
    {
        float b0v = ba[jt0 * 16 + n0], b1v = ba[jt1 * 16 + n0];
        c0 = (floatx4){b0v, b0v, b0v, b0v};
        c1 = (floatx4){b1v, b1v, b1v, b1v};
    }
    #pragma unroll
    for (int kk = 0; kk < IND / 32; ++kk) {
        // A frag: 8 f32 from zacc -> RNE bf16 pack
        union { bf16x8 v; unsigned int u[4]; } ua;
        #pragma unroll
        for (int j = 0; j < 4; ++j) {
            const float* zp = &zacc[(row0 + n0) * PAD + kk * 32 + quad * 8 + 2 * j];
            ua.u[j] = pack_bf2(zp[0], zp[1]);
        }
        bf16x8 br0 = *(const bf16x8*)&waT[(jt0 * 16 + n0) * LDW + kk * 32 + quad * 8];
        bf16x8 br1 = *(const bf16x8*)&waT[(jt1 * 16 + n0) * LDW + kk * 32 + quad * 8];
        c0 = __builtin_amdgcn_mfma_f32_16x16x32_bf16(ua.v, br0, c0, 0, 0, 0);
        c1 = __builtin_amdgcn_mfma_f32_16x16x32_bf16(ua.v, br1, c1, 0, 0, 0);
    }
    #pragma unroll
    for (int r = 0; r < 4; ++r) {
        int row = row0 + quad * 4 + r;
        t1buf[row * LDW + jt0 * 16 + n0] = f2bf(fmaxf(c0[r], 0.f));
        t1buf[row * LDW + jt1 * 16 + n0] = f2bf(fmaxf(c1[r], 0.f));
    }
    __syncthreads();

    {
        float b0v = bb[jt0 * 16 + n0], b1v = bb[jt1 * 16 + n0];
        c0 = (floatx4){b0v, b0v, b0v, b0v};
        c1 = (floatx4){b1v, b1v, b1v, b1v};
    }
    #pragma unroll
    for (int kk = 0; kk < 2; ++kk) {
        bf16x8 a   = *(const bf16x8*)&t1buf[(row0 + n0) * LDW + kk * 32 + quad * 8];
        bf16x8 br0 = *(const bf16x8*)&wbT[(jt0 * 16 + n0) * LDW + kk * 32 + quad * 8];
        bf16x8 br1 = *(const bf16x8*)&wbT[(jt1 * 16 + n0) * LDW + kk * 32 + quad * 8];
        c0 = __builtin_amdgcn_mfma_f32_16x16x32_bf16(a, br0, c0, 0, 0, 0);
        c1 = __builtin_amdgcn_mfma_f32_16x16x32_bf16(a, br1, c1, 0, 0, 0);
    }
    // zacc free since the t1 barrier; reuse as bf16 output staging
    unsigned short* zs = (unsigned short*)zacc;
    #pragma unroll
    for (int r = 0; r < 4; ++r) {
        int row = row0 + quad * 4 + r;
        float v0 = c0[r], v1 = c1[r];
        if (RELU_OUT) { v0 = fmaxf(v0, 0.f); v1 = fmaxf(v1, 0.f); }
        zs[row * LDW + jt0 * 16 + n0] = f2bf(v0);
        zs[row * LDW + jt1 * 16 + n0] = f2bf(v1);
    }
    __syncthreads();

    // ---- store: 512 threads x uint4 = full 64x128B tile ----
    {
        int nl = tid >> 3, c4 = tid & 7;
        int nodeo = tile0 + nl;
        if (nodeo < N) {
            uint4 v = *(const uint4*)&zs[nl * LDW + c4 * 8];
            ((uint4*)hout)[(size_t)nodeo * 8 + c4] = v;
        }
    }
}

// ---------------- global mean pool (partial sums over sorted batch) ----------------
__global__ void pool_kernel(const unsigned short* __restrict__ h, const int* __restrict__ batch,
                            float* __restrict__ pool, float* __restrict__ cnt, int N) {
    int lane = threadIdx.x;  // 64 threads
    int nblk = gridDim.x;
    int per = (N + nblk - 1) / nblk;
    int lo = blockIdx.x * per, hi = min(N, lo + per);
    if (lo >= hi) return;
    int cur = batch[lo];
    float acc = 0.f, c = 0.f;
    for (int n = lo; n < hi; ++n) {
        int b = batch[n];
        if (b != cur) {
            atomicAdd(&pool[cur * HD + lane], acc);
            if (lane == 0) atomicAdd(&cnt[cur], c);
            acc = 0.f; c = 0.f; cur = b;
        }
        acc += bf2f(h[(size_t)n * HD + lane]);
        c += 1.f;
    }
    atomicAdd(&pool[cur * HD + lane], acc);
    if (lane == 0) atomicAdd(&cnt[cur], c);
}

// ---------------- mean + linear head ----------------
__global__ void final_kernel(const float* __restrict__ pool, const float* __restrict__ cnt,
                             const float* __restrict__ lin_w, const float* __restrict__ lin_b,
                             float* __restrict__ out, int B) {
    int b = blockIdx.x;
    int lane = threadIdx.x;
    float c = fmaxf(cnt[b], 1.f);
    float v = pool[b * HD + lane] / c * lin_w[lane];
    for (int off = 32; off > 0; off >>= 1) v += __shfl_down(v, off);
    if (lane == 0) out[b] = v + lin_b[0];
}

extern "C" void kernel_launch(void* const* d_in, const int* in_sizes, int n_in,
                              void* d_out, int out_size, void* d_ws, size_t ws_size,
                              hipStream_t stream)
{
    const float* x   = (const float*)d_in[0];
    const float* pos = (const float*)d_in[1];
    const int*  eidx = (const int*)d_in[2];
    const int* batch = (const int*)d_in[3];
    const float* W1f = (const float*)d_in[4];
    const float* W1r = (const float*)d_in[5];
    const float* b1  = (const float*)d_in[6];
    const float* W2  = (const float*)d_in[7];
    const float* b2  = (const float*)d_in[8];
    const float* lw  = (const float*)d_in[9];
    const float* lb  = (const float*)d_in[10];

    int N = in_sizes[3];
    int E = in_sizes[2] / 2;
    int B = out_size;
    const int* src = eidx;
    const int* dst = eidx + E;

    char* ws = (char*)d_ws;
    size_t off = 0;
    auto alloc = [&](size_t bytes) -> void* {
        void* p = ws + off;
        off += (bytes + 255) & ~(size_t)255;
        return p;
    };
    unsigned short* bufA = (unsigned short*)alloc((size_t)N * HD * 2);
    unsigned short* bufB = (unsigned short*)alloc((size_t)N * HD * 2);
    int*   tstart = (int*)  alloc((size_t)(NBP + 1) * 4);
    unsigned int* epk = (unsigned int*)alloc((size_t)E * 4);
    float* pool   = (float*)alloc((size_t)B * HD * 4);
    float* cnt    = (float*)alloc((size_t)B * 4);
    int*   bcnt   = (int*)  alloc((size_t)NCHUNK * NBP * 4);
    int*   boff   = (int*)  alloc((size_t)NCHUNK * NBP * 4);
    unsigned short* wpk = (unsigned short*)alloc((size_t)NL * 2 * 64 * LDW * 2);

    hipMemsetAsync(pool, 0, (size_t)B * HD * 4, stream);
    hipMemsetAsync(cnt, 0, (size_t)B * 4, stream);

    int nb = (N + 63) >> 6;               // tile count (<= NBP for N <= 65536)
    int chunk = (E + NCHUNK - 1) / NCHUNK;

    build_h0_kernel<<<(N * 32 + 255) / 256, 256, 0, stream>>>(x, pos, bufA, N);
    prep_weights_kernel<<<(NL * 2 * 64 * LDW + 255) / 256, 256, 0, stream>>>(W1f, W1r, W2, wpk);
    tile_hist_kernel<<<NCHUNK, 256, 0, stream>>>(dst, E, chunk, bcnt, nb);
    tile_scan_kernel<<<1, 1024, 0, stream>>>(bcnt, boff, tstart, nb, E);
    tile_scatter_kernel<<<NCHUNK, 256, 0, stream>>>(src, dst, E, chunk, boff, epk, nb);

    const int gblocks = nb;
    const int PER_M = 64 * LDW;
    gin_layer_kernel<32, true><<<gblocks, 512, 0, stream>>>(
        bufA, tstart, epk, wpk + 0 * PER_M, wpk + 1 * PER_M, b1, b2, bufB, N);
    unsigned short* cur_in = bufB;
    unsigned short* cur_out = bufA;
    for (int l = 1; l < NL; ++l) {
        const unsigned short* wa = wpk + (size_t)(2 * l + 0) * PER_M;
        const unsigned short* wb = wpk + (size_t)(2 * l + 1) * PER_M;
        const float* ba = b1 + l * HD;
        const float* bb = b2 + l * HD;
        if (l < NL - 1)
            gin_layer_kernel<HD, true><<<gblocks, 512, 0, stream>>>(
                cur_in, tstart, epk, wa, wb, ba, bb, cur_out, N);
        else
            gin_layer_kernel<HD, false><<<gblocks, 512, 0, stream>>>(
                cur_in, tstart, epk, wa, wb, ba, bb, cur_out, N);
        unsigned short* tmp = cur_in; cur_in = cur_out; cur_out = tmp;
    }
    pool_kernel<<<512, 64, 0, stream>>>(cur_in, batch, pool, cnt, N);
    final_kernel<<<B, 64, 0, stream>>>(pool, cnt, lw, lb, (float*)d_out, B);
}

// Round 7
// 340.925 us; speedup vs baseline: 7.0635x; 7.0635x over previous
//
#include <hip/hip_runtime.h>
#include <stdint.h>

#define NF 29
#define HD 64
#define NL 7
#define LDW 72     // padded bf16 row stride (144 B, 16B-aligned)
#define NCHUNK 256 // edge chunks for binned scatter
#define BSH 8      // bucket = dst >> BSH  (256 nodes/bucket, needs N <= 65536)

typedef __attribute__((ext_vector_type(8))) __bf16 bf16x8;
typedef __attribute__((ext_vector_type(4))) float floatx4;

// fp32 -> bf16 bits, round-to-nearest-even
__device__ __forceinline__ unsigned short f2bf(float x) {
    unsigned u = __float_as_uint(x);
    unsigned r = (u + 0x7fffu + ((u >> 16) & 1u)) >> 16;
    return (unsigned short)r;
}
__device__ __forceinline__ unsigned pack_bf2(float x, float y) {
    return (unsigned)f2bf(x) | ((unsigned)f2bf(y) << 16);
}
__device__ __forceinline__ float bflo(uint32_t u) { return __uint_as_float(u << 16); }
__device__ __forceinline__ float bfhi(uint32_t u) { return __uint_as_float(u & 0xffff0000u); }

// ---------------- h0 = concat(x, pos) -> bf16 ----------------
__global__ void build_h0_kernel(const float* __restrict__ x, const float* __restrict__ pos,
                                unsigned short* __restrict__ h0, int N) {
    int t = blockIdx.x * blockDim.x + threadIdx.x;
    if (t >= N * 32) return;
    int n = t >> 5, f = t & 31;
    float v = (f < NF) ? x[n * NF + f] : pos[n * 3 + (f - NF)];
    h0[t] = f2bf(v);
}

// ---------------- weights: fp32 -> transposed, padded bf16 ----------------
__global__ void prep_weights_kernel(const float* __restrict__ W1f, const float* __restrict__ W1r,
                                    const float* __restrict__ W2, unsigned short* __restrict__ wpk) {
    const int PER_M = 64 * LDW;
    int t = blockIdx.x * blockDim.x + threadIdx.x;
    if (t >= NL * 2 * PER_M) return;
    int l = t / (2 * PER_M);
    int r = t - l * 2 * PER_M;
    int m = r / PER_M;
    int q = r - m * PER_M;
    int j = q / LDW, k = q - j * LDW;
    float v = 0.f;
    if (m == 0) {
        int ind = (l == 0) ? 32 : 64;
        if (k < ind) v = (l == 0) ? W1f[k * 64 + j]
                                  : W1r[(size_t)(l - 1) * 4096 + (size_t)k * 64 + j];
    } else {
        if (k < 64) v = W2[(size_t)l * 4096 + (size_t)k * 64 + j];
    }
    wpk[t] = f2bf(v);
}

// ---------------- CSR rowptr: node-degree hist + 3-phase scan ----------------
__global__ void hist_kernel(const int* __restrict__ dst, int E, int* __restrict__ deg) {
    int t = blockIdx.x * blockDim.x + threadIdx.x;
    if (t < E) atomicAdd(&deg[dst[t]], 1);
}

__global__ void scan1_kernel(const int* __restrict__ deg, int* __restrict__ part, int N) {
    int t = threadIdx.x;
    int i = blockIdx.x * 256 + t;
    int v = (i < N) ? deg[i] : 0;
    for (int off = 32; off > 0; off >>= 1) v += __shfl_down(v, off);
    __shared__ int ws[4];
    if ((t & 63) == 0) ws[t >> 6] = v;
    __syncthreads();
    if (t == 0) part[blockIdx.x] = ws[0] + ws[1] + ws[2] + ws[3];
}

__global__ void scan2_kernel(const int* __restrict__ part, int* __restrict__ partx, int nPart) {
    __shared__ int s[256];
    int t = threadIdx.x;
    s[t] = (t < nPart) ? part[t] : 0;
    __syncthreads();
    for (int off = 1; off < 256; off <<= 1) {
        int v = (t >= off) ? s[t - off] : 0;
        __syncthreads();
        s[t] += v;
        __syncthreads();
    }
    partx[t] = (t == 0) ? 0 : s[t - 1];
}

__global__ void scan3_kernel(const int* __restrict__ deg, const int* __restrict__ partx,
                             int* __restrict__ rowptr, int N) {
    int t = threadIdx.x;
    int lane = t & 63, wv = t >> 6;
    int i = blockIdx.x * 256 + t;
    int v = (i < N) ? deg[i] : 0;
    int incl = v;
    for (int off = 1; off < 64; off <<= 1) {
        int u = __shfl_up(incl, off);
        if (lane >= off) incl += u;
    }
    __shared__ int wsum[4];
    if (lane == 63) wsum[wv] = incl;
    __syncthreads();
    int offset = partx[blockIdx.x];
    for (int w = 0; w < wv; ++w) offset += wsum[w];
    int excl = offset + incl - v;
    if (i < N) rowptr[i] = excl;
    if (i == N - 1) rowptr[N] = excl + v;
}

// ---------------- binned scatter pass A1: per-(chunk,bucket) histogram ----------------
__global__ void bucket_hist_kernel(const int* __restrict__ dst, int E, int chunk,
                                   int* __restrict__ bcnt, int nbuk) {
    __shared__ int hist[256];
    int tid = threadIdx.x;
    hist[tid] = 0;
    __syncthreads();
    int lo = blockIdx.x * chunk, hi = min(E, lo + chunk);
    for (int e = lo + tid; e < hi; e += 256) atomicAdd(&hist[dst[e] >> BSH], 1);
    __syncthreads();
    if (tid < nbuk) bcnt[tid * NCHUNK + blockIdx.x] = hist[tid];
}

// ---------------- pass A2: bucket starts + per-(bucket,chunk) offsets ----------------
__global__ void bucket_scan_kernel(const int* __restrict__ bcnt, int* __restrict__ boff,
                                   int* __restrict__ bstart, int nbuk, int E) {
    __shared__ int s[256];
    int t = threadIdx.x;
    int tot = 0;
    if (t < nbuk)
        for (int blk = 0; blk < NCHUNK; ++blk) tot += bcnt[t * NCHUNK + blk];
    s[t] = tot;
    __syncthreads();
    for (int off = 1; off < 256; off <<= 1) {
        int v = (t >= off) ? s[t - off] : 0;
        __syncthreads();
        s[t] += v;
        __syncthreads();
    }
    int start = (t == 0) ? 0 : s[t - 1];
    if (t < nbuk) bstart[t] = start;
    if (t == 0) bstart[nbuk] = E;
    if (t < nbuk) {
        int run = start;
        for (int blk = 0; blk < NCHUNK; ++blk) {
            boff[t * NCHUNK + blk] = run;
            run += bcnt[t * NCHUNK + blk];
        }
    }
}

// ---------------- pass A3: scatter (src,dst) into bucket-grouped ebuf ----------------
__global__ void bucket_scatter_kernel(const int* __restrict__ src, const int* __restrict__ dst,
                                      int E, int chunk, const int* __restrict__ boff,
                                      int2* __restrict__ ebuf, int nbuk) {
    __shared__ int cur[256];
    int tid = threadIdx.x;
    if (tid < nbuk) cur[tid] = boff[tid * NCHUNK + blockIdx.x];
    __syncthreads();
    int lo = blockIdx.x * chunk, hi = min(E, lo + chunk);
    for (int e = lo + tid; e < hi; e += 256) {
        int d = dst[e];
        int p = atomicAdd(&cur[d >> BSH], 1);
        ebuf[p] = make_int2(src[e], d);
    }
}

// ---------------- pass B: within-bucket scatter to final CSR ----------------
__global__ void final_scatter_kernel(const int2* __restrict__ ebuf, const int* __restrict__ bstart,
                                     const int* __restrict__ rowptr, int* __restrict__ colsrc,
                                     int N) {
    __shared__ int cur[256];
    int b = blockIdx.x, tid = threadIdx.x;
    int node = (b << BSH) + tid;
    cur[tid] = (node < N) ? rowptr[node] : 0;
    __syncthreads();
    int lo = bstart[b], hi = bstart[b + 1];
    for (int e = lo + tid; e < hi; e += 256) {
        int2 ed = ebuf[e];
        int p = atomicAdd(&cur[ed.y & ((1 << BSH) - 1)], 1);
        colsrc[p] = ed.x;
    }
}

// ---------------- fused GIN layer: pipelined wide-load gather + MFMA MLP ----------------
// Block = 512 threads (8 waves) = 64-node tile. Group g (8 lanes) owns one node.
// Gather inner loop: batch of 8 edges; indices fetched with ONE coalesced load
// (lane j of group loads colsrc[e+j]) + __shfl broadcast, and the NEXT batch's
// index load is issued before this batch's row loads (2-stage pipeline), so the
// idx->row dependency latency is overlapped.
template<int IND, bool RELU_OUT>
__global__ __launch_bounds__(512, 8)
void gin_layer_kernel(const unsigned short* __restrict__ hin,
                      const int* __restrict__ rowptr, const int* __restrict__ colsrc,
                      const unsigned short* __restrict__ wAT, const unsigned short* __restrict__ wBT,
                      const float* __restrict__ ba, const float* __restrict__ bb,
                      unsigned short* __restrict__ hout, int N)
{
    __shared__ __align__(16) unsigned short zbuf[64 * LDW];
    __shared__ __align__(16) unsigned short t1buf[64 * LDW];
    __shared__ __align__(16) unsigned short waT[64 * LDW];
    __shared__ __align__(16) unsigned short wbT[64 * LDW];

    const int tid = threadIdx.x;
    const int lane = tid & 63;
    const int w = tid >> 6;
    const int tile0 = blockIdx.x * 64;

    // ---- stage pre-packed bf16 weights: pure uint4 memcpy ----
    {
        const uint4* a4 = (const uint4*)wAT;
        const uint4* b4 = (const uint4*)wBT;
        uint4* da = (uint4*)waT;
        uint4* db = (uint4*)wbT;
        for (int i = tid; i < 64 * LDW / 8; i += 512) { da[i] = a4[i]; db[i] = b4[i]; }
    }

    // ---- gather: group g (8 lanes) owns node tile0 + w*8 + g ----
    const uint4* hin4 = (const uint4*)hin;
    const int g = lane >> 3;
    const int j = lane & 7;
    const int node = tile0 + w * 8 + g;

    int rp;
    {
        int idx = tile0 + w * 8 + (lane < 9 ? lane : 8);
        if (idx > N) idx = N;
        rp = rowptr[idx];
    }
    int e0 = __shfl(rp, g);
    int e1 = __shfl(rp, g + 1);
    if (node >= N) { e0 = 0; e1 = 0; }

    float acc[8] = {0.f, 0.f, 0.f, 0.f, 0.f, 0.f, 0.f, 0.f};
    auto addrow = [&](uint4 u) {
        acc[0] += bflo(u.x); acc[1] += bfhi(u.x);
        acc[2] += bflo(u.y); acc[3] += bfhi(u.y);
        acc[4] += bflo(u.z); acc[5] += bfhi(u.z);
        acc[6] += bflo(u.w); acc[7] += bfhi(u.w);
    };

    if constexpr (IND == 64) {
        const int f4 = lane & 7;                       // 8 chunks x 16B = 128B row
        if (node < N) addrow(hin4[(size_t)node * 8 + f4]);   // self term
        int e = e0;
        // pipelined main loop: idx for batch i loaded during batch i-1
        int idxv = (e + j < e1) ? colsrc[e + j] : 0;
        for (; e + 7 < e1; e += 8) {
            int en = e + 8;
            int idx_next = (en + 7 < e1) ? colsrc[en + j]
                                         : ((en + j < e1) ? colsrc[en + j] : 0);
            int s[8];
            #pragma unroll
            for (int q = 0; q < 8; ++q) s[q] = __shfl(idxv, g * 8 + q);
            uint4 u[8];
            #pragma unroll
            for (int q = 0; q < 8; ++q) u[q] = hin4[(size_t)s[q] * 8 + f4];
            #pragma unroll
            for (int q = 0; q < 8; ++q) addrow(u[q]);
            idxv = idx_next;
        }
        // tail (< 8 edges): broadcast via shfl of the already-loaded idxv
        {
            int rem = e1 - e;
            #pragma unroll
            for (int q = 0; q < 8; ++q) {
                if (q < rem) {
                    int s = __shfl(idxv, g * 8 + q);
                    addrow(hin4[(size_t)s * 8 + f4]);
                }
            }
        }
        uint4 pk;
        pk.x = pack_bf2(acc[0], acc[1]); pk.y = pack_bf2(acc[2], acc[3]);
        pk.z = pack_bf2(acc[4], acc[5]); pk.w = pack_bf2(acc[6], acc[7]);
        *(uint4*)&zbuf[(w * 8 + g) * LDW + f4 * 8] = pk;
    } else {  // IND == 32: 4 chunks/row; group splits into p = 0/1 edge-pair lanes
        const int p = (lane >> 2) & 1;
        const int f4 = lane & 3;
        if (node < N && p == 0) addrow(hin4[(size_t)node * 4 + f4]);  // self once
        int e = e0 + p;
        for (; e + 7 < e1; e += 8) {
            int s0 = colsrc[e], s1 = colsrc[e + 2], s2 = colsrc[e + 4], s3 = colsrc[e + 6];
            uint4 u0 = hin4[(size_t)s0 * 4 + f4];
            uint4 u1 = hin4[(size_t)s1 * 4 + f4];
            uint4 u2 = hin4[(size_t)s2 * 4 + f4];
            uint4 u3 = hin4[(size_t)s3 * 4 + f4];
            addrow(u0); addrow(u1); addrow(u2); addrow(u3);
        }
        while (e < e1) { addrow(hin4[(size_t)colsrc[e] * 4 + f4]); e += 2; }
        #pragma unroll
        for (int i = 0; i < 8; ++i) acc[i] += __shfl_xor(acc[i], 4);
        if (p == 0) {
            uint4 pk;
            pk.x = pack_bf2(acc[0], acc[1]); pk.y = pack_bf2(acc[2], acc[3]);
            pk.z = pack_bf2(acc[4], acc[5]); pk.w = pack_bf2(acc[6], acc[7]);
            *(uint4*)&zbuf[(w * 8 + g) * LDW + f4 * 8] = pk;
        }
    }
    __syncthreads();

    // ---- MFMA MLP ----
    const int n0 = lane & 15, quad = lane >> 4;
    const int stripe = w & 3, jhalf = w >> 2;
    const int row0 = stripe * 16;
    const int jt0 = jhalf * 2, jt1 = jhalf * 2 + 1;

    floatx4 c0, c1;
    {
        float b0v = ba[jt0 * 16 + n0], b1v = ba[jt1 * 16 + n0];
        c0 = (floatx4){b0v, b0v, b0v, b0v};
        c1 = (floatx4){b1v, b1v, b1v, b1v};
    }
    #pragma unroll
    for (int kk = 0; kk < IND / 32; ++kk) {
        bf16x8 a   = *(const bf16x8*)&zbuf[(row0 + n0) * LDW + kk * 32 + quad * 8];
        bf16x8 br0 = *(const bf16x8*)&waT[(jt0 * 16 + n0) * LDW + kk * 32 + quad * 8];
        bf16x8 br1 = *(const bf16x8*)&waT[(jt1 * 16 + n0) * LDW + kk * 32 + quad * 8];
        c0 = __builtin_amdgcn_mfma_f32_16x16x32_bf16(a, br0, c0, 0, 0, 0);
        c1 = __builtin_amdgcn_mfma_f32_16x16x32_bf16(a, br1, c1, 0, 0, 0);
    }
    #pragma unroll
    for (int r = 0; r < 4; ++r) {
        int row = row0 + quad * 4 + r;
        t1buf[row * LDW + jt0 * 16 + n0] = f2bf(fmaxf(c0[r], 0.f));
        t1buf[row * LDW + jt1 * 16 + n0] = f2bf(fmaxf(c1[r], 0.f));
    }
    __syncthreads();

    {
        float b0v = bb[jt0 * 16 + n0], b1v = bb[jt1 * 16 + n0];
        c0 = (floatx4){b0v, b0v, b0v, b0v};
        c1 = (floatx4){b1v, b1v, b1v, b1v};
    }
    #pragma unroll
    for (int kk = 0; kk < 2; ++kk) {
        bf16x8 a   = *(const bf16x8*)&t1buf[(row0 + n0) * LDW + kk * 32 + quad * 8];
        bf16x8 br0 = *(const bf16x8*)&wbT[(jt0 * 16 + n0) * LDW + kk * 32 + quad * 8];
        bf16x8 br1 = *(const bf16x8*)&wbT[(jt1 * 16 + n0) * LDW + kk * 32 + quad * 8];
        c0 = __builtin_amdgcn_mfma_f32_16x16x32_bf16(a, br0, c0, 0, 0, 0);
        c1 = __builtin_amdgcn_mfma_f32_16x16x32_bf16(a, br1, c1, 0, 0, 0);
    }
    #pragma unroll
    for (int r = 0; r < 4; ++r) {
        int row = row0 + quad * 4 + r;
        float v0 = c0[r], v1 = c1[r];
        if (RELU_OUT) { v0 = fmaxf(v0, 0.f); v1 = fmaxf(v1, 0.f); }
        zbuf[row * LDW + jt0 * 16 + n0] = f2bf(v0);
        zbuf[row * LDW + jt1 * 16 + n0] = f2bf(v1);
    }
    __syncthreads();

    // ---- store: 512 threads x uint4 = full 64x128B tile, fully sequential ----
    {
        int nl = tid >> 3, c4 = tid & 7;
        int nodeo = tile0 + nl;
        if (nodeo < N) {
            uint4 v = *(const uint4*)&zbuf[nl * LDW + c4 * 8];
            ((uint4*)hout)[(size_t)nodeo * 8 + c4] = v;
        }
    }
}

// ---------------- global mean pool (partial sums over sorted batch) ----------------
__global__ void pool_kernel(const unsigned short* __restrict__ h, const int* __restrict__ batch,
                            float* __restrict__ pool, float* __restrict__ cnt, int N) {
    int lane = threadIdx.x;  // 64 threads
    int nblk = gridDim.x;
    int per = (N + nblk - 1) / nblk;
    int lo = blockIdx.x * per, hi = min(N, lo + per);
    if (lo >= hi) return;
    int cur = batch[lo];
    float acc = 0.f, c = 0.f;
    for (int n = lo; n < hi; ++n) {
        int b = batch[n];
        if (b != cur) {
            atomicAdd(&pool[cur * HD + lane], acc);
            if (lane == 0) atomicAdd(&cnt[cur], c);
            acc = 0.f; c = 0.f; cur = b;
        }
        acc += __uint_as_float((uint32_t)h[(size_t)n * HD + lane] << 16);
        c += 1.f;
    }
    atomicAdd(&pool[cur * HD + lane], acc);
    if (lane == 0) atomicAdd(&cnt[cur], c);
}

// ---------------- mean + linear head ----------------
__global__ void final_kernel(const float* __restrict__ pool, const float* __restrict__ cnt,
                             const float* __restrict__ lin_w, const float* __restrict__ lin_b,
                             float* __restrict__ out, int B) {
    int b = blockIdx.x;
    int lane = threadIdx.x;
    float c = fmaxf(cnt[b], 1.f);
    float v = pool[b * HD + lane] / c * lin_w[lane];
    for (int off = 32; off > 0; off >>= 1) v += __shfl_down(v, off);
    if (lane == 0) out[b] = v + lin_b[0];
}

extern "C" void kernel_launch(void* const* d_in, const int* in_sizes, int n_in,
                              void* d_out, int out_size, void* d_ws, size_t ws_size,
                              hipStream_t stream)
{
    const float* x   = (const float*)d_in[0];
    const float* pos = (const float*)d_in[1];
    const int*  eidx = (const int*)d_in[2];
    const int* batch = (const int*)d_in[3];
    const float* W1f = (const float*)d_in[4];
    const float* W1r = (const float*)d_in[5];
    const float* b1  = (const float*)d_in[6];
    const float* W2  = (const float*)d_in[7];
    const float* b2  = (const float*)d_in[8];
    const float* lw  = (const float*)d_in[9];
    const float* lb  = (const float*)d_in[10];

    int N = in_sizes[3];
    int E = in_sizes[2] / 2;
    int B = out_size;
    const int* src = eidx;
    const int* dst = eidx + E;

    char* ws = (char*)d_ws;
    size_t off = 0;
    auto alloc = [&](size_t bytes) -> void* {
        void* p = ws + off;
        off += (bytes + 255) & ~(size_t)255;
        return p;
    };
    unsigned short* bufA = (unsigned short*)alloc((size_t)N * HD * 2);
    unsigned short* bufB = (unsigned short*)alloc((size_t)N * HD * 2);
    int*   rowptr = (int*)  alloc((size_t)(N + 1) * 4);
    int*   deg    = (int*)  alloc((size_t)N * 4);
    int*   colsrc = (int*)  alloc((size_t)E * 4);
    int2*  ebuf   = (int2*) alloc((size_t)E * 8);
    float* pool   = (float*)alloc((size_t)B * HD * 4);
    float* cnt    = (float*)alloc((size_t)B * 4);
    int*   part   = (int*)  alloc(256 * 4);
    int*   partx  = (int*)  alloc(256 * 4);
    int*   bcnt   = (int*)  alloc((size_t)256 * NCHUNK * 4);
    int*   boff   = (int*)  alloc((size_t)256 * NCHUNK * 4);
    int*   bstart = (int*)  alloc(257 * 4);
    unsigned short* wpk = (unsigned short*)alloc((size_t)NL * 2 * 64 * LDW * 2);

    hipMemsetAsync(deg, 0, (size_t)N * 4, stream);
    hipMemsetAsync(pool, 0, (size_t)B * HD * 4, stream);
    hipMemsetAsync(cnt, 0, (size_t)B * 4, stream);

    int nPart = (N + 255) / 256;
    int nbuk = (N + (1 << BSH) - 1) >> BSH;   // <= 256 for N <= 65536
    int chunk = (E + NCHUNK - 1) / NCHUNK;

    build_h0_kernel<<<(N * 32 + 255) / 256, 256, 0, stream>>>(x, pos, bufA, N);
    prep_weights_kernel<<<(NL * 2 * 64 * LDW + 255) / 256, 256, 0, stream>>>(W1f, W1r, W2, wpk);
    hist_kernel<<<(E + 255) / 256, 256, 0, stream>>>(dst, E, deg);
    scan1_kernel<<<nPart, 256, 0, stream>>>(deg, part, N);
    scan2_kernel<<<1, 256, 0, stream>>>(part, partx, nPart);
    scan3_kernel<<<nPart, 256, 0, stream>>>(deg, partx, rowptr, N);
    bucket_hist_kernel<<<NCHUNK, 256, 0, stream>>>(dst, E, chunk, bcnt, nbuk);
    bucket_scan_kernel<<<1, 256, 0, stream>>>(bcnt, boff, bstart, nbuk, E);
    bucket_scatter_kernel<<<NCHUNK, 256, 0, stream>>>(src, dst, E, chunk, boff, ebuf, nbuk);
    final_scatter_kernel<<<nbuk, 256, 0, stream>>>(ebuf, bstart, rowptr, colsrc, N);

    const int gblocks = (N + 63) / 64;
    const int PER_M = 64 * LDW;
    gin_layer_kernel<32, true><<<gblocks, 512, 0, stream>>>(
        bufA, rowptr, colsrc, wpk + 0 * PER_M, wpk + 1 * PER_M, b1, b2, bufB, N);
    unsigned short* cur_in = bufB;
    unsigned short* cur_out = bufA;
    for (int l = 1; l < NL; ++l) {
        const unsigned short* wa = wpk + (size_t)(2 * l + 0) * PER_M;
        const unsigned short* wb = wpk + (size_t)(2 * l + 1) * PER_M;
        const float* ba = b1 + l * HD;
        const float* bb = b2 + l * HD;
        if (l < NL - 1)
            gin_layer_kernel<HD, true><<<gblocks, 512, 0, stream>>>(
                cur_in, rowptr, colsrc, wa, wb, ba, bb, cur_out, N);
        else
            gin_layer_kernel<HD, false><<<gblocks, 512, 0, stream>>>(
                cur_in, rowptr, colsrc, wa, wb, ba, bb, cur_out, N);
        unsigned short* tmp = cur_in; cur_in = cur_out; cur_out = tmp;
    }
    pool_kernel<<<512, 64, 0, stream>>>(cur_in, batch, pool, cnt, N);
    final_kernel<<<B, 64, 0, stream>>>(pool, cnt, lw, lb, (float*)d_out, B);
}

// Round 8
// 291.833 us; speedup vs baseline: 8.2517x; 1.1682x over previous
//
#include <hip/hip_runtime.h>
#include <stdint.h>

// Bench-fixed: N=50000 (<65536 so node ids fit u16), E=800000, B=50
#define NF 29
#define HD 64
#define NL 7
#define LDW 72     // padded bf16 row stride (144 B, 16B-aligned)
#define NCHUNK 256 // edge chunks for binned scatter
#define BSH 8      // bucket = dst >> 8 (256 nodes/bucket)
#define PER_M (64 * LDW)

typedef __attribute__((ext_vector_type(8))) __bf16 bf16x8;
typedef __attribute__((ext_vector_type(4))) float floatx4;

__device__ __forceinline__ unsigned short f2bf(float x) {
    unsigned u = __float_as_uint(x);
    unsigned r = (u + 0x7fffu + ((u >> 16) & 1u)) >> 16;
    return (unsigned short)r;
}
__device__ __forceinline__ unsigned pack_bf2(float x, float y) {
    return (unsigned)f2bf(x) | ((unsigned)f2bf(y) << 16);
}
__device__ __forceinline__ float bflo(uint32_t u) { return __uint_as_float(u << 16); }
__device__ __forceinline__ float bfhi(uint32_t u) { return __uint_as_float(u & 0xffff0000u); }

// ---------------- fused: h0 build + weight pre-pack ----------------
__global__ void init_kernel(const float* __restrict__ x, const float* __restrict__ pos,
                            unsigned short* __restrict__ h0,
                            const float* __restrict__ W1f, const float* __restrict__ W1r,
                            const float* __restrict__ W2, unsigned short* __restrict__ wpk,
                            int N) {
    int t = blockIdx.x * blockDim.x + threadIdx.x;
    if (t < NL * 2 * PER_M) {
        int l = t / (2 * PER_M);
        int r = t - l * 2 * PER_M;
        int m = r / PER_M;
        int q = r - m * PER_M;
        int j = q / LDW, k = q - j * LDW;
        float v = 0.f;
        if (m == 0) {
            int ind = (l == 0) ? 32 : 64;
            if (k < ind) v = (l == 0) ? W1f[k * 64 + j]
                                      : W1r[(size_t)(l - 1) * 4096 + (size_t)k * 64 + j];
        } else {
            if (k < 64) v = W2[(size_t)l * 4096 + (size_t)k * 64 + j];
        }
        wpk[t] = f2bf(v);
    }
    if (t < N * 32) {
        int n = t >> 5, f = t & 31;
        float v = (f < NF) ? x[n * NF + f] : pos[n * 3 + (f - NF)];
        h0[t] = f2bf(v);
    }
}

// ---------------- binned edge build ----------------
// A1: per-chunk bucket histogram + atomic bucket totals
__global__ void bucket_hist_kernel(const int* __restrict__ dst, int E, int chunk,
                                   int* __restrict__ bcnt, int* __restrict__ bsum) {
    __shared__ int hist[256];
    int tid = threadIdx.x;
    hist[tid] = 0;
    __syncthreads();
    int lo = blockIdx.x * chunk, hi = min(E, lo + chunk);
    for (int e = lo + tid; e < hi; e += 256) atomicAdd(&hist[dst[e] >> BSH], 1);
    __syncthreads();
    bcnt[tid * NCHUNK + blockIdx.x] = hist[tid];   // [bucket][chunk]
    if (hist[tid]) atomicAdd(&bsum[tid], hist[tid]);
}

// A2: scan bucket totals -> bstart; also rowptr[N]=E
__global__ void bstart_scan_kernel(const int* __restrict__ bsum, int* __restrict__ bstart,
                                   int* __restrict__ rowptr, int nbuk, int N, int E) {
    __shared__ int s[256];
    int t = threadIdx.x;
    s[t] = (t < nbuk) ? bsum[t] : 0;
    __syncthreads();
    for (int off = 1; off < 256; off <<= 1) {
        int v = (t >= off) ? s[t - off] : 0;
        __syncthreads();
        s[t] += v;
        __syncthreads();
    }
    bstart[t] = (t == 0) ? 0 : s[t - 1];
    if (t == 255) bstart[256] = s[255];
    if (t == 0) rowptr[N] = E;
}

// A3: per-bucket chunk-offset scan -> boffT[chunk][bucket]
__global__ void bucket_off_kernel(const int* __restrict__ bcnt, const int* __restrict__ bstart,
                                  int* __restrict__ boffT) {
    __shared__ int s[256];
    int b = blockIdx.x, t = threadIdx.x;
    int c = bcnt[b * NCHUNK + t];
    s[t] = c;
    __syncthreads();
    for (int off = 1; off < 256; off <<= 1) {
        int v = (t >= off) ? s[t - off] : 0;
        __syncthreads();
        s[t] += v;
        __syncthreads();
    }
    int excl = s[t] - c;
    boffT[t * 256 + b] = bstart[b] + excl;
}

// A4: scatter packed (dstLocal<<16 | src) into bucket-grouped ebuf
__global__ void bucket_scatter_kernel(const int* __restrict__ src, const int* __restrict__ dst,
                                      int E, int chunk, const int* __restrict__ boffT,
                                      unsigned int* __restrict__ ebuf) {
    __shared__ int cur[256];
    int tid = threadIdx.x, c = blockIdx.x;
    cur[tid] = boffT[c * 256 + tid];
    __syncthreads();
    int lo = c * chunk, hi = min(E, lo + chunk);
    for (int e = lo + tid; e < hi; e += 256) {
        int d = dst[e];
        int p = atomicAdd(&cur[d >> BSH], 1);
        ebuf[p] = (unsigned int)src[e] | ((unsigned int)(d & 255) << 16);
    }
}

// B: within-bucket: LDS degree hist -> LDS scan -> rowptr + colsrc(u16)
__global__ void final_scatter_kernel(const unsigned int* __restrict__ ebuf,
                                     const int* __restrict__ bstart,
                                     int* __restrict__ rowptr,
                                     unsigned short* __restrict__ colsrc, int N) {
    __shared__ int cnt[256];
    __shared__ int cur[256];
    __shared__ int s[256];
    int b = blockIdx.x, t = threadIdx.x;
    cnt[t] = 0;
    __syncthreads();
    int lo = bstart[b], hi = bstart[b + 1];
    for (int e = lo + t; e < hi; e += 256) atomicAdd(&cnt[ebuf[e] >> 16], 1);
    __syncthreads();
    int c = cnt[t];
    s[t] = c;
    __syncthreads();
    for (int off = 1; off < 256; off <<= 1) {
        int v = (t >= off) ? s[t - off] : 0;
        __syncthreads();
        s[t] += v;
        __syncthreads();
    }
    int base = lo + s[t] - c;
    int node = (b << BSH) + t;
    if (node < N) rowptr[node] = base;
    cur[t] = base;
    __syncthreads();
    for (int e = lo + t; e < hi; e += 256) {
        unsigned int ed = ebuf[e];
        int p = atomicAdd(&cur[ed >> 16], 1);
        colsrc[p] = (unsigned short)(ed & 0xffffu);
    }
}

// ---------------- fused GIN layer: wide-load gather + MFMA MLP ----------------
// Block = 512 threads (8 waves) = 64-node tile; group g (8 lanes) owns one node.
// LDS = zbuf + t1buf only (18.4 KB) -> 4 blocks/CU (32 waves, wave-slot cap).
// MFMA B-fragments read directly from global pre-packed weights (L1-resident).
template<int IND, bool RELU_OUT>
__global__ __launch_bounds__(512, 8)
void gin_layer_kernel(const unsigned short* __restrict__ hin,
                      const int* __restrict__ rowptr, const unsigned short* __restrict__ colsrc,
                      const unsigned short* __restrict__ wAT, const unsigned short* __restrict__ wBT,
                      const float* __restrict__ ba, const float* __restrict__ bb,
                      unsigned short* __restrict__ hout, int N)
{
    __shared__ __align__(16) unsigned short zbuf[64 * LDW];
    __shared__ __align__(16) unsigned short t1buf[64 * LDW];

    const int tid = threadIdx.x;
    const int lane = tid & 63;
    const int w = tid >> 6;
    const int tile0 = blockIdx.x * 64;

    // ---- gather ----
    const uint4* hin4 = (const uint4*)hin;
    const int g = lane >> 3;
    const int j = lane & 7;
    const int node = tile0 + w * 8 + g;

    int rp;
    {
        int idx = tile0 + w * 8 + (lane < 9 ? lane : 8);
        if (idx > N) idx = N;
        rp = rowptr[idx];
    }
    int e0 = __shfl(rp, g);
    int e1 = __shfl(rp, g + 1);
    if (node >= N) { e0 = 0; e1 = 0; }

    float acc[8] = {0.f, 0.f, 0.f, 0.f, 0.f, 0.f, 0.f, 0.f};
    auto addrow = [&](uint4 u) {
        acc[0] += bflo(u.x); acc[1] += bfhi(u.x);
        acc[2] += bflo(u.y); acc[3] += bfhi(u.y);
        acc[4] += bflo(u.z); acc[5] += bfhi(u.z);
        acc[6] += bflo(u.w); acc[7] += bfhi(u.w);
    };

    if constexpr (IND == 64) {
        const int f4 = lane & 7;
        if (node < N) addrow(hin4[(size_t)node * 8 + f4]);   // self term
        int e = e0;
        int idxv = (e + j < e1) ? (int)colsrc[e + j] : 0;
        for (; e + 7 < e1; e += 8) {
            int en = e + 8;
            int idx_next = (en + j < e1) ? (int)colsrc[en + j] : 0;
            int s[8];
            #pragma unroll
            for (int q = 0; q < 8; ++q) s[q] = __shfl(idxv, g * 8 + q);
            uint4 u[8];
            #pragma unroll
            for (int q = 0; q < 8; ++q) u[q] = hin4[(size_t)s[q] * 8 + f4];
            #pragma unroll
            for (int q = 0; q < 8; ++q) addrow(u[q]);
            idxv = idx_next;
        }
        {
            int rem = e1 - e;
            #pragma unroll
            for (int q = 0; q < 8; ++q) {
                if (q < rem) {
                    int s = __shfl(idxv, g * 8 + q);
                    addrow(hin4[(size_t)s * 8 + f4]);
                }
            }
        }
        uint4 pk;
        pk.x = pack_bf2(acc[0], acc[1]); pk.y = pack_bf2(acc[2], acc[3]);
        pk.z = pack_bf2(acc[4], acc[5]); pk.w = pack_bf2(acc[6], acc[7]);
        *(uint4*)&zbuf[(w * 8 + g) * LDW + f4 * 8] = pk;
    } else {  // IND == 32
        const int p = (lane >> 2) & 1;
        const int f4 = lane & 3;
        if (node < N && p == 0) addrow(hin4[(size_t)node * 4 + f4]);
        int e = e0 + p;
        for (; e + 7 < e1; e += 8) {
            int s0 = colsrc[e], s1 = colsrc[e + 2], s2 = colsrc[e + 4], s3 = colsrc[e + 6];
            uint4 u0 = hin4[(size_t)s0 * 4 + f4];
            uint4 u1 = hin4[(size_t)s1 * 4 + f4];
            uint4 u2 = hin4[(size_t)s2 * 4 + f4];
            uint4 u3 = hin4[(size_t)s3 * 4 + f4];
            addrow(u0); addrow(u1); addrow(u2); addrow(u3);
        }
        while (e < e1) { addrow(hin4[(size_t)colsrc[e] * 4 + f4]); e += 2; }
        #pragma unroll
        for (int i = 0; i < 8; ++i) acc[i] += __shfl_xor(acc[i], 4);
        if (p == 0) {
            uint4 pk;
            pk.x = pack_bf2(acc[0], acc[1]); pk.y = pack_bf2(acc[2], acc[3]);
            pk.z = pack_bf2(acc[4], acc[5]); pk.w = pack_bf2(acc[6], acc[7]);
            *(uint4*)&zbuf[(w * 8 + g) * LDW + f4 * 8] = pk;
        }
    }
    __syncthreads();

    // ---- MFMA MLP (B-frags direct from global, L1-hot) ----
    const int n0 = lane & 15, quad = lane >> 4;
    const int stripe = w & 3, jhalf = w >> 2;
    const int row0 = stripe * 16;
    const int jt0 = jhalf * 2, jt1 = jhalf * 2 + 1;

    floatx4 c0, c1;
    {
        float b0v = ba[jt0 * 16 + n0], b1v = ba[jt1 * 16 + n0];
        c0 = (floatx4){b0v, b0v, b0v, b0v};
        c1 = (floatx4){b1v, b1v, b1v, b1v};
    }
    #pragma unroll
    for (int kk = 0; kk < IND / 32; ++kk) {
        bf16x8 a   = *(const bf16x8*)&zbuf[(row0 + n0) * LDW + kk * 32 + quad * 8];
        bf16x8 br0 = *(const bf16x8*)&wAT[(jt0 * 16 + n0) * LDW + kk * 32 + quad * 8];
        bf16x8 br1 = *(const bf16x8*)&wAT[(jt1 * 16 + n0) * LDW + kk * 32 + quad * 8];
        c0 = __builtin_amdgcn_mfma_f32_16x16x32_bf16(a, br0, c0, 0, 0, 0);
        c1 = __builtin_amdgcn_mfma_f32_16x16x32_bf16(a, br1, c1, 0, 0, 0);
    }
    #pragma unroll
    for (int r = 0; r < 4; ++r) {
        int row = row0 + quad * 4 + r;
        t1buf[row * LDW + jt0 * 16 + n0] = f2bf(fmaxf(c0[r], 0.f));
        t1buf[row * LDW + jt1 * 16 + n0] = f2bf(fmaxf(c1[r], 0.f));
    }
    __syncthreads();

    {
        float b0v = bb[jt0 * 16 + n0], b1v = bb[jt1 * 16 + n0];
        c0 = (floatx4){b0v, b0v, b0v, b0v};
        c1 = (floatx4){b1v, b1v, b1v, b1v};
    }
    #pragma unroll
    for (int kk = 0; kk < 2; ++kk) {
        bf16x8 a   = *(const bf16x8*)&t1buf[(row0 + n0) * LDW + kk * 32 + quad * 8];
        bf16x8 br0 = *(const bf16x8*)&wBT[(jt0 * 16 + n0) * LDW + kk * 32 + quad * 8];
        bf16x8 br1 = *(const bf16x8*)&wBT[(jt1 * 16 + n0) * LDW + kk * 32 + quad * 8];
        c0 = __builtin_amdgcn_mfma_f32_16x16x32_bf16(a, br0, c0, 0, 0, 0);
        c1 = __builtin_amdgcn_mfma_f32_16x16x32_bf16(a, br1, c1, 0, 0, 0);
    }
    // zbuf free since the t1 barrier; reuse as output staging
    #pragma unroll
    for (int r = 0; r < 4; ++r) {
        int row = row0 + quad * 4 + r;
        float v0 = c0[r], v1 = c1[r];
        if (RELU_OUT) { v0 = fmaxf(v0, 0.f); v1 = fmaxf(v1, 0.f); }
        zbuf[row * LDW + jt0 * 16 + n0] = f2bf(v0);
        zbuf[row * LDW + jt1 * 16 + n0] = f2bf(v1);
    }
    __syncthreads();

    {
        int nl = tid >> 3, c4 = tid & 7;
        int nodeo = tile0 + nl;
        if (nodeo < N) {
            uint4 v = *(const uint4*)&zbuf[nl * LDW + c4 * 8];
            ((uint4*)hout)[(size_t)nodeo * 8 + c4] = v;
        }
    }
}

// ---------------- global mean pool ----------------
__global__ void pool_kernel(const unsigned short* __restrict__ h, const int* __restrict__ batch,
                            float* __restrict__ pool, float* __restrict__ cnt, int N) {
    int lane = threadIdx.x;  // 64 threads
    int nblk = gridDim.x;
    int per = (N + nblk - 1) / nblk;
    int lo = blockIdx.x * per, hi = min(N, lo + per);
    if (lo >= hi) return;
    int cur = batch[lo];
    float acc = 0.f, c = 0.f;
    for (int n = lo; n < hi; ++n) {
        int b = batch[n];
        if (b != cur) {
            atomicAdd(&pool[cur * HD + lane], acc);
            if (lane == 0) atomicAdd(&cnt[cur], c);
            acc = 0.f; c = 0.f; cur = b;
        }
        acc += __uint_as_float((uint32_t)h[(size_t)n * HD + lane] << 16);
        c += 1.f;
    }
    atomicAdd(&pool[cur * HD + lane], acc);
    if (lane == 0) atomicAdd(&cnt[cur], c);
}

// ---------------- mean + linear head ----------------
__global__ void final_kernel(const float* __restrict__ pool, const float* __restrict__ cnt,
                             const float* __restrict__ lin_w, const float* __restrict__ lin_b,
                             float* __restrict__ out, int B) {
    int b = blockIdx.x;
    int lane = threadIdx.x;
    float c = fmaxf(cnt[b], 1.f);
    float v = pool[b * HD + lane] / c * lin_w[lane];
    for (int off = 32; off > 0; off >>= 1) v += __shfl_down(v, off);
    if (lane == 0) out[b] = v + lin_b[0];
}

extern "C" void kernel_launch(void* const* d_in, const int* in_sizes, int n_in,
                              void* d_out, int out_size, void* d_ws, size_t ws_size,
                              hipStream_t stream)
{
    const float* x   = (const float*)d_in[0];
    const float* pos = (const float*)d_in[1];
    const int*  eidx = (const int*)d_in[2];
    const int* batch = (const int*)d_in[3];
    const float* W1f = (const float*)d_in[4];
    const float* W1r = (const float*)d_in[5];
    const float* b1  = (const float*)d_in[6];
    const float* W2  = (const float*)d_in[7];
    const float* b2  = (const float*)d_in[8];
    const float* lw  = (const float*)d_in[9];
    const float* lb  = (const float*)d_in[10];

    int N = in_sizes[3];
    int E = in_sizes[2] / 2;
    int B = out_size;
    const int* src = eidx;
    const int* dst = eidx + E;

    char* ws = (char*)d_ws;
    size_t off = 0;
    auto alloc = [&](size_t bytes) -> void* {
        void* p = ws + off;
        off += (bytes + 255) & ~(size_t)255;
        return p;
    };
    unsigned short* bufA = (unsigned short*)alloc((size_t)N * HD * 2);
    unsigned short* bufB = (unsigned short*)alloc((size_t)N * HD * 2);
    int*   rowptr = (int*)  alloc((size_t)(N + 1) * 4);
    unsigned short* colsrc = (unsigned short*)alloc((size_t)E * 2);
    unsigned int* ebuf = (unsigned int*)alloc((size_t)E * 4);
    float* pool   = (float*)alloc((size_t)B * HD * 4);
    float* cnt    = (float*)alloc((size_t)B * 4);
    int*   bcnt   = (int*)  alloc((size_t)256 * NCHUNK * 4);
    int*   boffT  = (int*)  alloc((size_t)NCHUNK * 256 * 4);
    int*   bsum   = (int*)  alloc(256 * 4);
    int*   bstart = (int*)  alloc(257 * 4);
    unsigned short* wpk = (unsigned short*)alloc((size_t)NL * 2 * PER_M * 2);

    hipMemsetAsync(bsum, 0, 256 * 4, stream);
    hipMemsetAsync(pool, 0, (size_t)B * HD * 4, stream);
    hipMemsetAsync(cnt, 0, (size_t)B * 4, stream);

    int nbuk = (N + 255) >> BSH;
    int chunk = (E + NCHUNK - 1) / NCHUNK;

    init_kernel<<<(N * 32 + 255) / 256, 256, 0, stream>>>(x, pos, bufA, W1f, W1r, W2, wpk, N);
    bucket_hist_kernel<<<NCHUNK, 256, 0, stream>>>(dst, E, chunk, bcnt, bsum);
    bstart_scan_kernel<<<1, 256, 0, stream>>>(bsum, bstart, rowptr, nbuk, N, E);
    bucket_off_kernel<<<nbuk, 256, 0, stream>>>(bcnt, bstart, boffT);
    bucket_scatter_kernel<<<NCHUNK, 256, 0, stream>>>(src, dst, E, chunk, boffT, ebuf);
    final_scatter_kernel<<<nbuk, 256, 0, stream>>>(ebuf, bstart, rowptr, colsrc, N);

    const int gblocks = (N + 63) / 64;
    gin_layer_kernel<32, true><<<gblocks, 512, 0, stream>>>(
        bufA, rowptr, colsrc, wpk + 0 * PER_M, wpk + 1 * PER_M, b1, b2, bufB, N);
    unsigned short* cur_in = bufB;
    unsigned short* cur_out = bufA;
    for (int l = 1; l < NL; ++l) {
        const unsigned short* wa = wpk + (size_t)(2 * l + 0) * PER_M;
        const unsigned short* wb = wpk + (size_t)(2 * l + 1) * PER_M;
        const float* ba = b1 + l * HD;
        const float* bb = b2 + l * HD;
        if (l < NL - 1)
            gin_layer_kernel<HD, true><<<gblocks, 512, 0, stream>>>(
                cur_in, rowptr, colsrc, wa, wb, ba, bb, cur_out, N);
        else
            gin_layer_kernel<HD, false><<<gblocks, 512, 0, stream>>>(
                cur_in, rowptr, colsrc, wa, wb, ba, bb, cur_out, N);
        unsigned short* tmp = cur_in; cur_in = cur_out; cur_out = tmp;
    }
    pool_kernel<<<512, 64, 0, stream>>>(cur_in, batch, pool, cnt, N);
    final_kernel<<<B, 64, 0, stream>>>(pool, cnt, lw, lb, (float*)d_out, B);
}